// Round 1
// 224.858 us; speedup vs baseline: 1.0510x; 1.0510x over previous
//
#include <hip/hip_runtime.h>
#include <hip/hip_fp16.h>
#include <stdint.h>

// MaxUnpooling2D scatter-add, two-phase (bin by output tile, then reduce).
//
// Target word: w = (batch << 22) | (idx & ~63) | c
//   decode: out_c == C == 64  =>  y*out_w*out_c + x*out_c + f == (idx&~63) + c
//
// Phase 1: 1024 blocks x 8192 elems, 1024 thr; LDS counting sort by bin =
//   w>>14 (2048 bins); entries packed to 4B: idx14 in [29:16], fp16 value in
//   [15:0]. Coalesced segment dump + per-(block,bin) start table (u16: starts
//   are <= 8192 so 16 bits suffice -> table traffic halved vs u32).
// Phase 1.5: transpose table (u16) to bin-major so p2 bounds reads coalesce.
// Phase 2: 2048 blocks (one per bin), 1024 thr; 4 lanes walk a slice
//   cooperatively (round-6 structure, known-good).
// Round 8: u16 table/tt (-17 MB/iter), nontemporal loads of in/idx (dead
//   after p1; LLC is thrashed by the 536MB poison fill each iter anyway) and
//   nontemporal stores of out (write-only) to keep seg/tt LLC-resident for
//   p2's 16B-granule slice reads.
// NOTE: dur_us includes ~128us of harness re-poison fills (512MiB d_ws etc.)
//   we cannot control; controllable budget is p1 + pt + p2.

typedef float f32x4 __attribute__((ext_vector_type(4)));
typedef int   i32x4 __attribute__((ext_vector_type(4)));

constexpr int  BINS            = 2048;
constexpr int  P1_BLOCKS       = 1024;
constexpr int  ELEMS_PER_BLOCK = 8192;       // elements binned per p1 block
constexpr int  WORDS_PER_BIN   = 1 << 14;    // 16384 output words per bin
constexpr int  IN_PER_B_LOG2   = 20;         // 128*128*64 = 2^20
constexpr int  OUT_PER_B_LOG2  = 22;         // 256*256*64 = 2^22
constexpr long long N = 8LL << IN_PER_B_LOG2;            // 8,388,608
constexpr size_t SEG_BYTES   = (size_t)P1_BLOCKS * ELEMS_PER_BLOCK * 4; // 33.5 MB
constexpr size_t TABLE_BYTES = (size_t)P1_BLOCKS * BINS * 2;            // 4.2 MB (u16)
constexpr size_t WS_NEEDED   = SEG_BYTES + 2 * TABLE_BYTES;             // 41.9 MB

__device__ __forceinline__ uint32_t pack_entry(uint32_t w, float v) {
    const uint16_t h = __half_as_ushort(__float2half(v));
    return ((w & 0x3FFFu) << 16) | (uint32_t)h;
}

__global__ __launch_bounds__(1024, 8) void p1_bin(
    const f32x4* __restrict__ in4, const i32x4* __restrict__ idx4,
    uint32_t* __restrict__ seg, uint16_t* __restrict__ table)
{
    __shared__ uint32_t hist[BINS];                          // counts -> cursor
    __shared__ uint32_t wave_tot[16];
    __shared__ alignas(16) uint32_t staging[ELEMS_PER_BLOCK];// 32 KB
    const int blk = blockIdx.x, t = threadIdx.x;
    const int lane = t & 63, wid = t >> 6;

    hist[2 * t]     = 0;
    hist[2 * t + 1] = 0;
    __syncthreads();

    f32x4 v[2]; i32x4 ix[2];
    const int base4 = blk * (ELEMS_PER_BLOCK / 4);   // float4 index base
    #pragma unroll
    for (int j = 0; j < 2; ++j) {
        // nontemporal: in/idx are dead after this kernel; don't occupy LLC.
        v[j]  = __builtin_nontemporal_load(in4  + base4 + j * 1024 + t);
        ix[j] = __builtin_nontemporal_load(idx4 + base4 + j * 1024 + t);
    }

    // histogram over bins
    #pragma unroll
    for (int j = 0; j < 2; ++j) {
        const int e0 = (base4 + j * 1024 + t) * 4;       // flat input elem idx
        const uint32_t hi = (uint32_t)(e0 >> IN_PER_B_LOG2) << OUT_PER_B_LOG2;
        const int c0 = e0 & 63;
        const int* ip = (const int*)&ix[j];
        #pragma unroll
        for (int l = 0; l < 4; ++l) {
            uint32_t w = hi | ((uint32_t)ip[l] & ~63u) | (uint32_t)(c0 + l);
            atomicAdd(&hist[w >> 14], 1u);
        }
    }
    __syncthreads();

    // exclusive scan of the 2048 counts (thread t owns bins 2t, 2t+1):
    // wave-level shfl scan + 16-entry cross-wave fixup.
    uint32_t c0 = hist[2 * t], c1 = hist[2 * t + 1];
    uint32_t local = c0 + c1, inc = local;
    #pragma unroll
    for (int d = 1; d < 64; d <<= 1) {
        uint32_t up = __shfl_up(inc, d, 64);
        if (lane >= d) inc += up;
    }
    if (lane == 63) wave_tot[wid] = inc;
    __syncthreads();
    uint32_t woff = 0;
    for (int w = 0; w < wid; ++w) woff += wave_tot[w];
    const uint32_t excl = woff + inc - local;     // exclusive prefix, thread t
    const uint32_t s0 = excl, s1 = excl + c0;

    // per-(block,bin) start table: starts <= 8192 fit u16; pack the thread's
    // two starts into one u32 store (coalesced 4B/thread), blk-major.
    ((uint32_t*)(table + (size_t)blk * BINS))[t] = ((uint32_t)s1 << 16) | s0;
    // cursor init (thread t only rewrites the 2 entries it read)
    hist[2 * t] = s0;
    hist[2 * t + 1] = s1;
    __syncthreads();

    // counting-sort scatter into LDS staging (4B packed entries)
    #pragma unroll
    for (int j = 0; j < 2; ++j) {
        const int e0 = (base4 + j * 1024 + t) * 4;
        const uint32_t hi = (uint32_t)(e0 >> IN_PER_B_LOG2) << OUT_PER_B_LOG2;
        const int cc = e0 & 63;
        const int*   ip = (const int*)&ix[j];
        const float* vp = (const float*)&v[j];
        #pragma unroll
        for (int l = 0; l < 4; ++l) {
            uint32_t w = hi | ((uint32_t)ip[l] & ~63u) | (uint32_t)(cc + l);
            uint32_t pos = atomicAdd(&hist[w >> 14], 1u);
            staging[pos] = pack_entry(w, vp[l]);
        }
    }
    __syncthreads();

    // coalesced dump: 32 KB staging -> global segment (16 B/lane, 2 iters).
    // Normal (cacheable) stores: seg is re-read by p2 and fits LLC.
    const uint4* s4 = (const uint4*)staging;
    uint4* g4 = (uint4*)(seg + (size_t)blk * ELEMS_PER_BLOCK);
    #pragma unroll
    for (int j = 0; j < ELEMS_PER_BLOCK * 4 / 16 / 1024; ++j)
        g4[j * 1024 + t] = s4[j * 1024 + t];
}

// Transpose u16 [P1_BLOCKS][BINS] -> [BINS][P1_BLOCKS] (8.4 MB traffic).
__global__ __launch_bounds__(1024) void p_transpose(
    const uint16_t* __restrict__ table, uint16_t* __restrict__ tt)
{
    __shared__ uint16_t tile[64][66];     // 66*2B=132B row: u16 col reads 2-way
    const int bx = blockIdx.x;            // bin-tile   (BINS/64   = 32)
    const int by = blockIdx.y;            // block-tile (P1_BLOCKS/64 = 16)
    const int tx = threadIdx.x & 63;
    const int ty = threadIdx.x >> 6;      // 0..15
    #pragma unroll
    for (int j = 0; j < 4; ++j) {
        const int row = by * 64 + ty + j * 16;                  // p1 block
        tile[ty + j * 16][tx] = table[(size_t)row * BINS + bx * 64 + tx];
    }
    __syncthreads();
    #pragma unroll
    for (int j = 0; j < 4; ++j) {
        const int orow = bx * 64 + ty + j * 16;                 // bin
        tt[(size_t)orow * P1_BLOCKS + by * 64 + tx] = tile[tx][ty + j * 16];
    }
}

__global__ __launch_bounds__(1024, 8) void p2_reduce(
    const uint32_t* __restrict__ seg, const uint16_t* __restrict__ tt,
    float4* __restrict__ out4)
{
    __shared__ alignas(16) float acc[WORDS_PER_BIN];   // 64 KB output tile
    __shared__ uint16_t ss[P1_BLOCKS];                 // slice starts
    __shared__ uint16_t ee[P1_BLOCKS];                 // slice ends
    const int b = blockIdx.x, t = threadIdx.x;
    #pragma unroll
    for (int j = 0; j < WORDS_PER_BIN / 1024; ++j) acc[t + j * 1024] = 0.f;

    // bin-major u16 table: fully coalesced bounds loads (2 KB/row)
    ss[t] = tt[(size_t)b * P1_BLOCKS + t];
    ee[t] = (b == BINS - 1) ? (uint16_t)ELEMS_PER_BLOCK
                            : tt[(size_t)(b + 1) * P1_BLOCKS + t];
    __syncthreads();

    // 4 lanes walk one slice together (round-6 structure, known-good).
    const int g  = t >> 2;        // group id in [0,256)
    const int gl = t & 3;         // lane within group
    #pragma unroll
    for (int r = 0; r < 4; ++r) {
        const int sl = g + r * 256;                    // slice for this group
        const uint32_t s = ss[sl], e = ee[sl];
        const uint32_t* sp = seg + (size_t)sl * ELEMS_PER_BLOCK;
        for (uint32_t k = s + gl; k < e; k += 4) {
            const uint32_t en = sp[k];
            const float val = __half2float(__ushort_as_half((uint16_t)(en & 0xFFFFu)));
            atomicAdd(&acc[en >> 16], val);            // ds_add_f32
        }
    }
    __syncthreads();

    // nontemporal out dump: write-only, never re-read -> keep LLC for seg/tt.
    const f32x4* a4 = (const f32x4*)acc;
    f32x4* o = (f32x4*)out4 + (size_t)b * (WORDS_PER_BIN / 4);
    #pragma unroll
    for (int j = 0; j < WORDS_PER_BIN / 4 / 1024; ++j)     // 4 iters
        __builtin_nontemporal_store(a4[j * 1024 + t], o + j * 1024 + t);
}

// ---------- fallback path (ws too small): zero + global atomics ----------
__global__ __launch_bounds__(256) void zero_out(float4* __restrict__ out)
{
    int t = blockIdx.x * blockDim.x + threadIdx.x;
    out[t] = float4{0.f, 0.f, 0.f, 0.f};
}

__global__ __launch_bounds__(256) void unpool_scatter(
    const float* __restrict__ in, const int* __restrict__ idx,
    float* __restrict__ out)
{
    int t = blockIdx.x * blockDim.x + threadIdx.x;
    float4 v  = reinterpret_cast<const float4*>(in)[t];
    int4   i4 = reinterpret_cast<const int4*>(idx)[t];
    int e0 = t << 2;
    int out_b = (e0 >> IN_PER_B_LOG2) << OUT_PER_B_LOG2;
    int c0 = e0 & 63;
    unsafeAtomicAdd(out + (out_b | (i4.x & ~63) | (c0 + 0)), v.x);
    unsafeAtomicAdd(out + (out_b | (i4.y & ~63) | (c0 + 1)), v.y);
    unsafeAtomicAdd(out + (out_b | (i4.z & ~63) | (c0 + 2)), v.z);
    unsafeAtomicAdd(out + (out_b | (i4.w & ~63) | (c0 + 3)), v.w);
}

extern "C" void kernel_launch(void* const* d_in, const int* in_sizes, int n_in,
                              void* d_out, int out_size, void* d_ws, size_t ws_size,
                              hipStream_t stream)
{
    const float* in  = (const float*)d_in[0];
    const int*   idx = (const int*)d_in[1];
    float*       out = (float*)d_out;

    if (ws_size >= WS_NEEDED) {
        uint32_t* seg   = (uint32_t*)d_ws;
        uint16_t* table = (uint16_t*)((char*)d_ws + SEG_BYTES);
        uint16_t* tt    = (uint16_t*)((char*)d_ws + SEG_BYTES + TABLE_BYTES);
        p1_bin<<<P1_BLOCKS, 1024, 0, stream>>>(
            (const f32x4*)in, (const i32x4*)idx, seg, table);
        p_transpose<<<dim3(BINS / 64, P1_BLOCKS / 64), 1024, 0, stream>>>(table, tt);
        p2_reduce<<<BINS, 1024, 0, stream>>>(seg, tt, (float4*)out);
    } else {
        zero_out<<<(out_size / 4) / 256, 256, 0, stream>>>((float4*)out);
        unpool_scatter<<<(int)(N / 4) / 256, 256, 0, stream>>>(in, idx, out);
    }
}

// Round 2
// 218.616 us; speedup vs baseline: 1.0810x; 1.0285x over previous
//
#include <hip/hip_runtime.h>
#include <hip/hip_fp16.h>
#include <stdint.h>

// MaxUnpooling2D scatter-add, two-phase (bin by output tile, then reduce).
//
// Target word: w = (batch << 22) | (idx & ~63) | c
//   decode: out_c == C == 64  =>  y*out_w*out_c + x*out_c + f == (idx&~63) + c
//
// Phase 1: 512 blocks x 16384 elems, 1024 thr; LDS counting sort by bin =
//   w>>14 (2048 bins); entries packed to 4B: idx14 in [29:16], fp16 value in
//   [15:0]. Coalesced segment dump + per-(block,bin) start table (u16).
// Phase 1.5: transpose table (u16) to bin-major so p2 bounds reads coalesce.
// Phase 2: 2048 blocks (one per bin), 1024 thr; 8 lanes walk a slice
//   cooperatively (avg slice len 8 -> 32B contiguous per group iteration).
// Round 9: 1024->512 p1 blocks (16384 elems each). Doubles avg p2 slice
//   length (4->8 entries) halving effective slice-read traffic + walk count;
//   halves table/tt traffic again. p1 holds only ix[] across the scan and
//   streams values with depth-1 prefetch in the scatter phase to stay under
//   the 64-VGPR cap needed for 2 blocks/CU at 72KB LDS.
// NOTE: dur_us includes ~128us of harness re-poison fills (512MiB d_ws etc.)
//   we cannot control; controllable budget is p1 + pt + p2.

typedef float f32x4 __attribute__((ext_vector_type(4)));
typedef int   i32x4 __attribute__((ext_vector_type(4)));

constexpr int  BINS            = 2048;
constexpr int  P1_BLOCKS       = 512;
constexpr int  ELEMS_PER_BLOCK = 16384;      // elements binned per p1 block
constexpr int  WORDS_PER_BIN   = 1 << 14;    // 16384 output words per bin
constexpr int  IN_PER_B_LOG2   = 20;         // 128*128*64 = 2^20
constexpr int  OUT_PER_B_LOG2  = 22;         // 256*256*64 = 2^22
constexpr long long N = 8LL << IN_PER_B_LOG2;            // 8,388,608
constexpr size_t SEG_BYTES   = (size_t)P1_BLOCKS * ELEMS_PER_BLOCK * 4; // 33.5 MB
constexpr size_t TABLE_BYTES = (size_t)P1_BLOCKS * BINS * 2;            // 2.1 MB (u16)
constexpr size_t WS_NEEDED   = SEG_BYTES + 2 * TABLE_BYTES;             // 37.7 MB

__device__ __forceinline__ uint32_t pack_entry(uint32_t w, float v) {
    const uint16_t h = __half_as_ushort(__float2half(v));
    return ((w & 0x3FFFu) << 16) | (uint32_t)h;
}

__global__ __launch_bounds__(1024, 8) void p1_bin(
    const f32x4* __restrict__ in4, const i32x4* __restrict__ idx4,
    uint32_t* __restrict__ seg, uint16_t* __restrict__ table)
{
    __shared__ uint32_t hist[BINS];                          // counts -> cursor
    __shared__ uint32_t wave_tot[16];
    __shared__ alignas(16) uint32_t staging[ELEMS_PER_BLOCK];// 64 KB
    const int blk = blockIdx.x, t = threadIdx.x;
    const int lane = t & 63, wid = t >> 6;

    hist[2 * t]     = 0;
    hist[2 * t + 1] = 0;
    __syncthreads();

    // Only indices persist across the scan (16 VGPRs); values are streamed
    // in during the scatter phase (depth-1 prefetch) to fit the 64-VGPR cap.
    i32x4 ix[4];
    const int base4 = blk * (ELEMS_PER_BLOCK / 4);   // float4 index base
    #pragma unroll
    for (int j = 0; j < 4; ++j)
        ix[j] = __builtin_nontemporal_load(idx4 + base4 + j * 1024 + t);

    // histogram over bins
    #pragma unroll
    for (int j = 0; j < 4; ++j) {
        const int e0 = (base4 + j * 1024 + t) * 4;       // flat input elem idx
        const uint32_t hi = (uint32_t)(e0 >> IN_PER_B_LOG2) << OUT_PER_B_LOG2;
        const int c0 = e0 & 63;
        const int* ip = (const int*)&ix[j];
        #pragma unroll
        for (int l = 0; l < 4; ++l) {
            uint32_t w = hi | ((uint32_t)ip[l] & ~63u) | (uint32_t)(c0 + l);
            atomicAdd(&hist[w >> 14], 1u);
        }
    }
    __syncthreads();

    // exclusive scan of the 2048 counts (thread t owns bins 2t, 2t+1):
    // wave-level shfl scan + 16-entry cross-wave fixup.
    uint32_t c0 = hist[2 * t], c1 = hist[2 * t + 1];
    uint32_t local = c0 + c1, inc = local;
    #pragma unroll
    for (int d = 1; d < 64; d <<= 1) {
        uint32_t up = __shfl_up(inc, d, 64);
        if (lane >= d) inc += up;
    }
    if (lane == 63) wave_tot[wid] = inc;
    __syncthreads();
    uint32_t woff = 0;
    for (int w = 0; w < wid; ++w) woff += wave_tot[w];
    const uint32_t excl = woff + inc - local;     // exclusive prefix, thread t
    const uint32_t s0 = excl, s1 = excl + c0;

    // per-(block,bin) start table: starts <= 16384 fit u16; pack the thread's
    // two starts into one u32 store (coalesced 4B/thread), blk-major.
    ((uint32_t*)(table + (size_t)blk * BINS))[t] = ((uint32_t)s1 << 16) | s0;
    // cursor init (thread t only rewrites the 2 entries it read)
    hist[2 * t] = s0;
    hist[2 * t + 1] = s1;
    __syncthreads();

    // counting-sort scatter into LDS staging (4B packed entries),
    // values streamed with depth-1 prefetch.
    f32x4 vcur = __builtin_nontemporal_load(in4 + base4 + t);
    #pragma unroll
    for (int j = 0; j < 4; ++j) {
        f32x4 vnext;
        if (j < 3) vnext = __builtin_nontemporal_load(in4 + base4 + (j + 1) * 1024 + t);
        const int e0 = (base4 + j * 1024 + t) * 4;
        const uint32_t hi = (uint32_t)(e0 >> IN_PER_B_LOG2) << OUT_PER_B_LOG2;
        const int cc = e0 & 63;
        const int*   ip = (const int*)&ix[j];
        const float* vp = (const float*)&vcur;
        #pragma unroll
        for (int l = 0; l < 4; ++l) {
            uint32_t w = hi | ((uint32_t)ip[l] & ~63u) | (uint32_t)(cc + l);
            uint32_t pos = atomicAdd(&hist[w >> 14], 1u);
            staging[pos] = pack_entry(w, vp[l]);
        }
        vcur = vnext;
    }
    __syncthreads();

    // coalesced dump: 64 KB staging -> global segment (16 B/lane, 4 iters).
    // Normal (cacheable) stores: seg is re-read by p2 and fits LLC.
    const uint4* s4 = (const uint4*)staging;
    uint4* g4 = (uint4*)(seg + (size_t)blk * ELEMS_PER_BLOCK);
    #pragma unroll
    for (int j = 0; j < ELEMS_PER_BLOCK * 4 / 16 / 1024; ++j)
        g4[j * 1024 + t] = s4[j * 1024 + t];
}

// Transpose u16 [P1_BLOCKS][BINS] -> [BINS][P1_BLOCKS] (4.2 MB traffic).
__global__ __launch_bounds__(1024) void p_transpose(
    const uint16_t* __restrict__ table, uint16_t* __restrict__ tt)
{
    __shared__ uint16_t tile[64][66];     // 66*2B=132B row: u16 col reads 2-way
    const int bx = blockIdx.x;            // bin-tile   (BINS/64   = 32)
    const int by = blockIdx.y;            // block-tile (P1_BLOCKS/64 = 8)
    const int tx = threadIdx.x & 63;
    const int ty = threadIdx.x >> 6;      // 0..15
    #pragma unroll
    for (int j = 0; j < 4; ++j) {
        const int row = by * 64 + ty + j * 16;                  // p1 block
        tile[ty + j * 16][tx] = table[(size_t)row * BINS + bx * 64 + tx];
    }
    __syncthreads();
    #pragma unroll
    for (int j = 0; j < 4; ++j) {
        const int orow = bx * 64 + ty + j * 16;                 // bin
        tt[(size_t)orow * P1_BLOCKS + by * 64 + tx] = tile[tx][ty + j * 16];
    }
}

__global__ __launch_bounds__(1024, 8) void p2_reduce(
    const uint32_t* __restrict__ seg, const uint16_t* __restrict__ tt,
    float4* __restrict__ out4)
{
    __shared__ alignas(16) float acc[WORDS_PER_BIN];   // 64 KB output tile
    __shared__ uint16_t ss[P1_BLOCKS];                 // slice starts (1 KB)
    __shared__ uint16_t ee[P1_BLOCKS];                 // slice ends   (1 KB)
    const int b = blockIdx.x, t = threadIdx.x;
    #pragma unroll
    for (int j = 0; j < WORDS_PER_BIN / 4 / 1024; ++j)
        ((f32x4*)acc)[t + j * 1024] = f32x4{0.f, 0.f, 0.f, 0.f};

    // bin-major u16 table: coalesced bounds loads (1 KB/row)
    if (t < P1_BLOCKS) {
        ss[t] = tt[(size_t)b * P1_BLOCKS + t];
        ee[t] = (b == BINS - 1) ? (uint16_t)ELEMS_PER_BLOCK
                                : tt[(size_t)(b + 1) * P1_BLOCKS + t];
    }
    __syncthreads();

    // 8 lanes walk one slice together (avg slice len 8 -> 32B contiguous).
    const int g  = t >> 3;        // group id in [0,128)
    const int gl = t & 7;         // lane within group
    #pragma unroll
    for (int r = 0; r < 4; ++r) {
        const int sl = g + r * 128;                    // slice for this group
        const uint32_t s = ss[sl], e = ee[sl];
        const uint32_t* sp = seg + (size_t)sl * ELEMS_PER_BLOCK;
        for (uint32_t k = s + gl; k < e; k += 8) {
            const uint32_t en = sp[k];
            const float val = __half2float(__ushort_as_half((uint16_t)(en & 0xFFFFu)));
            atomicAdd(&acc[en >> 16], val);            // ds_add_f32
        }
    }
    __syncthreads();

    // nontemporal out dump: write-only, never re-read -> keep LLC for seg/tt.
    const f32x4* a4 = (const f32x4*)acc;
    f32x4* o = (f32x4*)out4 + (size_t)b * (WORDS_PER_BIN / 4);
    #pragma unroll
    for (int j = 0; j < WORDS_PER_BIN / 4 / 1024; ++j)     // 4 iters
        __builtin_nontemporal_store(a4[j * 1024 + t], o + j * 1024 + t);
}

// ---------- fallback path (ws too small): zero + global atomics ----------
__global__ __launch_bounds__(256) void zero_out(float4* __restrict__ out)
{
    int t = blockIdx.x * blockDim.x + threadIdx.x;
    out[t] = float4{0.f, 0.f, 0.f, 0.f};
}

__global__ __launch_bounds__(256) void unpool_scatter(
    const float* __restrict__ in, const int* __restrict__ idx,
    float* __restrict__ out)
{
    int t = blockIdx.x * blockDim.x + threadIdx.x;
    float4 v  = reinterpret_cast<const float4*>(in)[t];
    int4   i4 = reinterpret_cast<const int4*>(idx)[t];
    int e0 = t << 2;
    int out_b = (e0 >> IN_PER_B_LOG2) << OUT_PER_B_LOG2;
    int c0 = e0 & 63;
    unsafeAtomicAdd(out + (out_b | (i4.x & ~63) | (c0 + 0)), v.x);
    unsafeAtomicAdd(out + (out_b | (i4.y & ~63) | (c0 + 1)), v.y);
    unsafeAtomicAdd(out + (out_b | (i4.z & ~63) | (c0 + 2)), v.z);
    unsafeAtomicAdd(out + (out_b | (i4.w & ~63) | (c0 + 3)), v.w);
}

extern "C" void kernel_launch(void* const* d_in, const int* in_sizes, int n_in,
                              void* d_out, int out_size, void* d_ws, size_t ws_size,
                              hipStream_t stream)
{
    const float* in  = (const float*)d_in[0];
    const int*   idx = (const int*)d_in[1];
    float*       out = (float*)d_out;

    if (ws_size >= WS_NEEDED) {
        uint32_t* seg   = (uint32_t*)d_ws;
        uint16_t* table = (uint16_t*)((char*)d_ws + SEG_BYTES);
        uint16_t* tt    = (uint16_t*)((char*)d_ws + SEG_BYTES + TABLE_BYTES);
        p1_bin<<<P1_BLOCKS, 1024, 0, stream>>>(
            (const f32x4*)in, (const i32x4*)idx, seg, table);
        p_transpose<<<dim3(BINS / 64, P1_BLOCKS / 64), 1024, 0, stream>>>(table, tt);
        p2_reduce<<<BINS, 1024, 0, stream>>>(seg, tt, (float4*)out);
    } else {
        zero_out<<<(out_size / 4) / 256, 256, 0, stream>>>((float4*)out);
        unpool_scatter<<<(int)(N / 4) / 256, 256, 0, stream>>>(in, idx, out);
    }
}

// Round 3
// 217.523 us; speedup vs baseline: 1.0865x; 1.0050x over previous
//
#include <hip/hip_runtime.h>
#include <hip/hip_fp16.h>
#include <stdint.h>

// MaxUnpooling2D scatter-add, two-phase (bin by output tile, then reduce).
//
// Target word: w = (batch << 22) | (idx & ~63) | c
//   decode: out_c == C == 64  =>  y*out_w*out_c + x*out_c + f == (idx&~63) + c
//
// Phase 1: 256 blocks x 32768 elems, 1024 thr; LDS counting sort by bin =
//   w>>14 (2048 bins); entries packed to 4B: idx14 in [29:16], fp16 value in
//   [15:0]. Coalesced segment dump + per-(block,bin) start table (u16).
// Phase 1.5: transpose table (u16) to bin-major so p2 bounds reads coalesce.
// Phase 2: 2048 blocks (one per bin), 1024 thr; 16 lanes walk a slice
//   cooperatively (avg slice len 16 -> 64B per group iteration).
// Round 10: 512->256 p1 blocks (32768 elems each, 128KB staging, 1 blk/CU).
//   Doubles avg p2 slice length (8->16 = full cacheline), halves slice-walk
//   count and table/tt traffic again. 1 blk/CU raises per-wave VGPR budget
//   to 128 so all 8 idx vectors stay resident across the scan.
// NOTE: dur_us includes ~128us of harness re-poison fills (512MiB d_ws etc.)
//   we cannot control; controllable budget is p1 + pt + p2.

typedef float f32x4 __attribute__((ext_vector_type(4)));
typedef int   i32x4 __attribute__((ext_vector_type(4)));

constexpr int  BINS            = 2048;
constexpr int  P1_BLOCKS       = 256;
constexpr int  ELEMS_PER_BLOCK = 32768;      // elements binned per p1 block
constexpr int  WORDS_PER_BIN   = 1 << 14;    // 16384 output words per bin
constexpr int  IN_PER_B_LOG2   = 20;         // 128*128*64 = 2^20
constexpr int  OUT_PER_B_LOG2  = 22;         // 256*256*64 = 2^22
constexpr long long N = 8LL << IN_PER_B_LOG2;            // 8,388,608
constexpr size_t SEG_BYTES   = (size_t)P1_BLOCKS * ELEMS_PER_BLOCK * 4; // 33.5 MB
constexpr size_t TABLE_BYTES = (size_t)P1_BLOCKS * BINS * 2;            // 1.0 MB (u16)
constexpr size_t WS_NEEDED   = SEG_BYTES + 2 * TABLE_BYTES;             // 35.7 MB

__device__ __forceinline__ uint32_t pack_entry(uint32_t w, float v) {
    const uint16_t h = __half_as_ushort(__float2half(v));
    return ((w & 0x3FFFu) << 16) | (uint32_t)h;
}

__global__ __launch_bounds__(1024, 4) void p1_bin(
    const f32x4* __restrict__ in4, const i32x4* __restrict__ idx4,
    uint32_t* __restrict__ seg, uint16_t* __restrict__ table)
{
    __shared__ uint32_t hist[BINS];                          // counts -> cursor
    __shared__ uint32_t wave_tot[16];
    __shared__ alignas(16) uint32_t staging[ELEMS_PER_BLOCK];// 128 KB
    const int blk = blockIdx.x, t = threadIdx.x;
    const int lane = t & 63, wid = t >> 6;

    hist[2 * t]     = 0;
    hist[2 * t + 1] = 0;
    __syncthreads();

    // All 8 idx vectors persist across the scan (32 VGPRs; 1 blk/CU gives a
    // 128-VGPR budget). Values are streamed in during the scatter phase.
    i32x4 ix[8];
    const int base4 = blk * (ELEMS_PER_BLOCK / 4);   // float4 index base
    #pragma unroll
    for (int j = 0; j < 8; ++j)
        ix[j] = __builtin_nontemporal_load(idx4 + base4 + j * 1024 + t);

    // histogram over bins
    #pragma unroll
    for (int j = 0; j < 8; ++j) {
        const int e0 = (base4 + j * 1024 + t) * 4;       // flat input elem idx
        const uint32_t hi = (uint32_t)(e0 >> IN_PER_B_LOG2) << OUT_PER_B_LOG2;
        const int c0 = e0 & 63;
        const int* ip = (const int*)&ix[j];
        #pragma unroll
        for (int l = 0; l < 4; ++l) {
            uint32_t w = hi | ((uint32_t)ip[l] & ~63u) | (uint32_t)(c0 + l);
            atomicAdd(&hist[w >> 14], 1u);
        }
    }
    __syncthreads();

    // exclusive scan of the 2048 counts (thread t owns bins 2t, 2t+1):
    // wave-level shfl scan + 16-entry cross-wave fixup.
    uint32_t c0 = hist[2 * t], c1 = hist[2 * t + 1];
    uint32_t local = c0 + c1, inc = local;
    #pragma unroll
    for (int d = 1; d < 64; d <<= 1) {
        uint32_t up = __shfl_up(inc, d, 64);
        if (lane >= d) inc += up;
    }
    if (lane == 63) wave_tot[wid] = inc;
    __syncthreads();
    uint32_t woff = 0;
    for (int w = 0; w < wid; ++w) woff += wave_tot[w];
    const uint32_t excl = woff + inc - local;     // exclusive prefix, thread t
    const uint32_t s0 = excl, s1 = excl + c0;

    // per-(block,bin) start table: starts <= 32768 fit u16; pack the thread's
    // two starts into one u32 store (coalesced 4B/thread), blk-major.
    ((uint32_t*)(table + (size_t)blk * BINS))[t] = ((uint32_t)s1 << 16) | s0;
    // cursor init (thread t only rewrites the 2 entries it read)
    hist[2 * t] = s0;
    hist[2 * t + 1] = s1;
    __syncthreads();

    // counting-sort scatter into LDS staging (4B packed entries),
    // values streamed with depth-1 prefetch.
    f32x4 vcur = __builtin_nontemporal_load(in4 + base4 + t);
    #pragma unroll
    for (int j = 0; j < 8; ++j) {
        f32x4 vnext;
        if (j < 7) vnext = __builtin_nontemporal_load(in4 + base4 + (j + 1) * 1024 + t);
        const int e0 = (base4 + j * 1024 + t) * 4;
        const uint32_t hi = (uint32_t)(e0 >> IN_PER_B_LOG2) << OUT_PER_B_LOG2;
        const int cc = e0 & 63;
        const int*   ip = (const int*)&ix[j];
        const float* vp = (const float*)&vcur;
        #pragma unroll
        for (int l = 0; l < 4; ++l) {
            uint32_t w = hi | ((uint32_t)ip[l] & ~63u) | (uint32_t)(cc + l);
            uint32_t pos = atomicAdd(&hist[w >> 14], 1u);
            staging[pos] = pack_entry(w, vp[l]);
        }
        vcur = vnext;
    }
    __syncthreads();

    // coalesced dump: 128 KB staging -> global segment (16 B/lane, 8 iters).
    // Normal (cacheable) stores: seg is re-read by p2 and fits LLC.
    const uint4* s4 = (const uint4*)staging;
    uint4* g4 = (uint4*)(seg + (size_t)blk * ELEMS_PER_BLOCK);
    #pragma unroll
    for (int j = 0; j < ELEMS_PER_BLOCK * 4 / 16 / 1024; ++j)
        g4[j * 1024 + t] = s4[j * 1024 + t];
}

// Transpose u16 [P1_BLOCKS][BINS] -> [BINS][P1_BLOCKS] (2.1 MB traffic).
__global__ __launch_bounds__(1024) void p_transpose(
    const uint16_t* __restrict__ table, uint16_t* __restrict__ tt)
{
    __shared__ uint16_t tile[64][66];     // 66*2B=132B row: u16 col reads 2-way
    const int bx = blockIdx.x;            // bin-tile   (BINS/64   = 32)
    const int by = blockIdx.y;            // block-tile (P1_BLOCKS/64 = 4)
    const int tx = threadIdx.x & 63;
    const int ty = threadIdx.x >> 6;      // 0..15
    #pragma unroll
    for (int j = 0; j < 4; ++j) {
        const int row = by * 64 + ty + j * 16;                  // p1 block
        tile[ty + j * 16][tx] = table[(size_t)row * BINS + bx * 64 + tx];
    }
    __syncthreads();
    #pragma unroll
    for (int j = 0; j < 4; ++j) {
        const int orow = bx * 64 + ty + j * 16;                 // bin
        tt[(size_t)orow * P1_BLOCKS + by * 64 + tx] = tile[tx][ty + j * 16];
    }
}

__global__ __launch_bounds__(1024, 8) void p2_reduce(
    const uint32_t* __restrict__ seg, const uint16_t* __restrict__ tt,
    float4* __restrict__ out4)
{
    __shared__ alignas(16) float acc[WORDS_PER_BIN];   // 64 KB output tile
    __shared__ uint16_t ss[P1_BLOCKS];                 // slice starts (512 B)
    __shared__ uint16_t ee[P1_BLOCKS];                 // slice ends   (512 B)
    const int b = blockIdx.x, t = threadIdx.x;
    #pragma unroll
    for (int j = 0; j < WORDS_PER_BIN / 4 / 1024; ++j)
        ((f32x4*)acc)[t + j * 1024] = f32x4{0.f, 0.f, 0.f, 0.f};

    // bin-major u16 table: coalesced bounds loads (512 B/row)
    if (t < P1_BLOCKS) {
        ss[t] = tt[(size_t)b * P1_BLOCKS + t];
        ee[t] = (b == BINS - 1) ? (uint16_t)ELEMS_PER_BLOCK
                                : tt[(size_t)(b + 1) * P1_BLOCKS + t];
    }
    __syncthreads();

    // 16 lanes walk one slice together (avg slice len 16 -> 64B/iteration).
    const int g  = t >> 4;        // group id in [0,64)
    const int gl = t & 15;        // lane within group
    #pragma unroll
    for (int r = 0; r < 4; ++r) {
        const int sl = g + r * 64;                     // slice for this group
        const uint32_t s = ss[sl], e = ee[sl];
        const uint32_t* sp = seg + (size_t)sl * ELEMS_PER_BLOCK;
        for (uint32_t k = s + gl; k < e; k += 16) {
            const uint32_t en = sp[k];
            const float val = __half2float(__ushort_as_half((uint16_t)(en & 0xFFFFu)));
            atomicAdd(&acc[en >> 16], val);            // ds_add_f32
        }
    }
    __syncthreads();

    // nontemporal out dump: write-only, never re-read -> keep LLC for seg/tt.
    const f32x4* a4 = (const f32x4*)acc;
    f32x4* o = (f32x4*)out4 + (size_t)b * (WORDS_PER_BIN / 4);
    #pragma unroll
    for (int j = 0; j < WORDS_PER_BIN / 4 / 1024; ++j)     // 4 iters
        __builtin_nontemporal_store(a4[j * 1024 + t], o + j * 1024 + t);
}

// ---------- fallback path (ws too small): zero + global atomics ----------
__global__ __launch_bounds__(256) void zero_out(float4* __restrict__ out)
{
    int t = blockIdx.x * blockDim.x + threadIdx.x;
    out[t] = float4{0.f, 0.f, 0.f, 0.f};
}

__global__ __launch_bounds__(256) void unpool_scatter(
    const float* __restrict__ in, const int* __restrict__ idx,
    float* __restrict__ out)
{
    int t = blockIdx.x * blockDim.x + threadIdx.x;
    float4 v  = reinterpret_cast<const float4*>(in)[t];
    int4   i4 = reinterpret_cast<const int4*>(idx)[t];
    int e0 = t << 2;
    int out_b = (e0 >> IN_PER_B_LOG2) << OUT_PER_B_LOG2;
    int c0 = e0 & 63;
    unsafeAtomicAdd(out + (out_b | (i4.x & ~63) | (c0 + 0)), v.x);
    unsafeAtomicAdd(out + (out_b | (i4.y & ~63) | (c0 + 1)), v.y);
    unsafeAtomicAdd(out + (out_b | (i4.z & ~63) | (c0 + 2)), v.z);
    unsafeAtomicAdd(out + (out_b | (i4.w & ~63) | (c0 + 3)), v.w);
}

extern "C" void kernel_launch(void* const* d_in, const int* in_sizes, int n_in,
                              void* d_out, int out_size, void* d_ws, size_t ws_size,
                              hipStream_t stream)
{
    const float* in  = (const float*)d_in[0];
    const int*   idx = (const int*)d_in[1];
    float*       out = (float*)d_out;

    if (ws_size >= WS_NEEDED) {
        uint32_t* seg   = (uint32_t*)d_ws;
        uint16_t* table = (uint16_t*)((char*)d_ws + SEG_BYTES);
        uint16_t* tt    = (uint16_t*)((char*)d_ws + SEG_BYTES + TABLE_BYTES);
        p1_bin<<<P1_BLOCKS, 1024, 0, stream>>>(
            (const f32x4*)in, (const i32x4*)idx, seg, table);
        p_transpose<<<dim3(BINS / 64, P1_BLOCKS / 64), 1024, 0, stream>>>(table, tt);
        p2_reduce<<<BINS, 1024, 0, stream>>>(seg, tt, (float4*)out);
    } else {
        zero_out<<<(out_size / 4) / 256, 256, 0, stream>>>((float4*)out);
        unpool_scatter<<<(int)(N / 4) / 256, 256, 0, stream>>>(in, idx, out);
    }
}